// Round 1
// baseline (1111.713 us; speedup 1.0000x reference)
//
#include <hip/hip_runtime.h>
#include <hip/hip_bf16.h>
#include <stdint.h>

// Problem constants
#define T_STEPS 128
#define BATCH   2048
#define IN_DIM  18
#define HID     256

// Fragment repack (same layout as R3)
#define NT   48
#define KT0  9
#define KT1  16
#define L0_FRAGS 432
#define L1_FRAGS 768
#define TOT_FRAGS 1200

// d_ws layout (total need ~10.1 MB)
// [0, 1.2MB)        weight fragments
// CNT_OFF           counters: CNTA, CNTB1 (BC hf=0), CNTB2 (BC hf=1)
// H1_OFF            h1 ring, depth 4: 4*64*16KB = 4MB
// P_OFF             h2-half exchange ring, depth 4: 4*128*8KB = 4MB
#define CNT_OFF  1310720u
#define CNTA(g)  (CNT_OFF + (uint32_t)(g) * 64u)
#define CNTB1(g) (CNT_OFF + 4096u + (uint32_t)(g) * 64u)
#define CNTB2(g) (CNT_OFF + 8192u + (uint32_t)(g) * 64u)
#define H1_OFF   1441792u
#define H1SLOT(t, g) (H1_OFF + (uint32_t)(((((t) & 3) * 64) + (g)) * 16384))
#define P_OFF    5898240u
#define PSLOT(t, g, hf) (P_OFF + (uint32_t)(((((t) & 3) * 128) + (g) * 2 + (hf)) * 8192))

using frag_ab = __attribute__((ext_vector_type(8))) short;
using f32x4   = __attribute__((ext_vector_type(4))) float;
using uint4v  = __attribute__((ext_vector_type(4))) unsigned int;

__device__ __forceinline__ unsigned short f2bf(float f) {
  unsigned int u = __float_as_uint(f);
  u = (u + 0x7fffu + ((u >> 16) & 1u)) >> 16;  // RNE
  return (unsigned short)u;
}
__device__ __forceinline__ float bf2f(unsigned short v) {
  return __uint_as_float((uint32_t)v << 16);
}
__device__ __forceinline__ float sigmoidf_(float v) {
  return 1.f / (1.f + __expf(-v));
}
__device__ __forceinline__ float tanhf_(float v) {
  float a = fabsf(v);
  float e = __expf(-2.f * a);
  float r = (1.f - e) / (1.f + e);
  return v < 0.f ? -r : r;
}
__device__ __forceinline__ f32x4 mfma16(frag_ab a, frag_ab b, f32x4 c) {
  return __builtin_amdgcn_mfma_f32_16x16x32_bf16(a, b, c, 0, 0, 0);
}

// ---------------------------------------------------------------------------
// Prologue 1: fp32 weights -> bf16 MFMA B-fragments (layout as R3).
// ---------------------------------------------------------------------------
__global__ __launch_bounds__(256) void repack_w(
    const float* __restrict__ Wih0, const float* __restrict__ Whh0,
    const float* __restrict__ Wih1, const float* __restrict__ Whh1,
    unsigned short* __restrict__ wq)
{
  int g = blockIdx.x * 256 + threadIdx.x;
  if (g >= TOT_FRAGS * 64) return;
  int f = g >> 6;
  int L = g & 63;
  int q = L >> 4, c16 = L & 15;
  unsigned short v[8];
  if (f < L0_FRAGS) {
    int n = f / KT0, kt = f - n * KT0;
    int col = n * 16 + c16;
    if (kt == 0) {
      #pragma unroll
      for (int j = 0; j < 8; ++j) {
        int k = q * 8 + j;
        v[j] = (k < IN_DIM) ? f2bf(Wih0[col * IN_DIM + k]) : (unsigned short)0;
      }
    } else {
      int kb = (kt - 1) * 32 + q * 8;
      #pragma unroll
      for (int j = 0; j < 8; ++j) v[j] = f2bf(Whh0[col * HID + kb + j]);
    }
  } else {
    int f1 = f - L0_FRAGS;
    int n = f1 / KT1, kt = f1 - n * KT1;
    int col = n * 16 + c16;
    const float* __restrict__ W = (kt < 8) ? Wih1 : Whh1;
    int kb = (kt & 7) * 32 + q * 8;
    #pragma unroll
    for (int j = 0; j < 8; ++j) v[j] = f2bf(W[col * HID + kb + j]);
  }
  frag_ab pv;
  #pragma unroll
  for (int j = 0; j < 8; ++j) pv[j] = (short)v[j];
  *(frag_ab*)((char*)wq + ((size_t)f << 10) + (size_t)(L << 4)) = pv;
}

// ---------------------------------------------------------------------------
// Prologue 2: zero the counters (d_ws poisoned each launch).
// ---------------------------------------------------------------------------
__global__ __launch_bounds__(256) void clear_cnt(uint32_t* __restrict__ c) {
  int i = blockIdx.x * 256 + threadIdx.x;
  if (i < 3072) c[i] = 0;
}

// ---------------------------------------------------------------------------
// 2-stage pipeline:
//   A   (64 blocks): layer-0 GRU, exports h1(t) A-frags (unchanged from R3).
//   BC (128 blocks): layer-1 fused. Column-split: hf=0 owns h2 cols [0,128),
//     hf=1 owns [128,256). Waves 0-7: xg = h1 @ W_ih1^T (K-tiles 0-7);
//     waves 8-15: hg = h2 @ W_hh1^T (K-tiles 8-15). xg never leaves registers
//     (the old stage-B global roundtrip is gone). Wave pair (w, w+8) swaps one
//     M-tile of f32 partials via LDS; each wave finishes gates for one M-tile.
//     Partner blocks exchange 8 KB h2 halves per step via sc0/sc1 ring.
// ---------------------------------------------------------------------------
__global__ __launch_bounds__(1024) void gru_pipe(
    const float* __restrict__ x,
    const float* __restrict__ bih0, const float* __restrict__ bhh0,
    const float* __restrict__ bih1, const float* __restrict__ bhh1,
    const float* __restrict__ fcw,  const float* __restrict__ fcb,
    char* __restrict__ ws,
    float* __restrict__ out)
{
  __shared__ __align__(16) char smem[115712];

  const int tid  = threadIdx.x;
  const int wave = tid >> 6;
  const int lane = tid & 63;
  const int q    = lane >> 4;
  const int c16  = lane & 15;
  const int bid  = blockIdx.x;
  const uint32_t lane16 = (uint32_t)(lane << 4);
  int dead = 0;

#define BARRIER() asm volatile("s_waitcnt lgkmcnt(0)\n\ts_barrier" ::: "memory")
#define ISSUE3(sl, oR, oZ, oN)                                              \
  asm volatile("global_load_dwordx4 %0, %3, %6\n\t"                         \
               "global_load_dwordx4 %1, %4, %6\n\t"                         \
               "global_load_dwordx4 %2, %5, %6"                             \
               : "=&v"(rr_[sl]), "=&v"(rz_[sl]), "=&v"(rn_[sl])             \
               : "v"((uint32_t)(oR)), "v"((uint32_t)(oZ)),                  \
                 "v"((uint32_t)(oN)), "s"(ws)                               \
               : "memory")
#define WAIT3(sl, NSTR)                                                     \
  asm volatile("s_waitcnt vmcnt(" NSTR ")"                                  \
               : "+v"(rr_[sl]), "+v"(rz_[sl]), "+v"(rn_[sl]) :: "memory")
#define SCLOAD4(dst, off)                                                   \
  asm volatile("global_load_dwordx4 %0, %1, %2 sc0 sc1"                     \
               : "=&v"(dst) : "v"((uint32_t)(off)), "s"(ws) : "memory")
#define SCSTORE4(off, val)                                                  \
  asm volatile("global_store_dwordx4 %0, %1, %2 sc0 sc1"                    \
               :: "v"((uint32_t)(off)), "v"(val), "s"(ws) : "memory")
#define SCSTOREH(off, val)                                                  \
  asm volatile("global_store_short %0, %1, %2 sc0 sc1"                      \
               :: "v"((uint32_t)(off)), "v"((uint32_t)(val)), "s"(ws)       \
               : "memory")
#define PUBLISH(off, val)                                                   \
  asm volatile("global_store_dword %0, %1, %2 sc0 sc1"                      \
               :: "v"((uint32_t)(off)), "v"((uint32_t)(val)), "s"(ws)       \
               : "memory")
#define POLL(off, target)                                                   \
  do {                                                                      \
    int tgt = (target);                                                     \
    if (tgt > 0) {                                                          \
      int it = 0, bound = dead ? 64 : (1 << 17);                            \
      for (;;) {                                                            \
        uint32_t v_;                                                        \
        asm volatile("global_load_dword %0, %1, %2 sc0 sc1\n\t"             \
                     "s_waitcnt vmcnt(0)"                                   \
                     : "=&v"(v_) : "v"((uint32_t)(off)), "s"(ws)            \
                     : "memory");                                           \
        if ((int)v_ >= tgt) break;                                          \
        if (++it >= bound) { dead = 1; break; }                             \
        __builtin_amdgcn_s_sleep(2);                                        \
      }                                                                     \
    }                                                                       \
  } while (0)

  // =========================================================================
  if (bid < 64) {
    // ----------------------------- Stage A: layer 0 -----------------------
    const int g = bid, row0 = g * 32;
    unsigned short (*h1b)[264] = (unsigned short (*)[264])smem;       // [2*32][264]
    unsigned short (*xs)[32]   = (unsigned short (*)[32])(smem + 33792); // [2*32][32]
    for (int i = tid; i < 2 * 32 * 264; i += 1024) ((unsigned short*)smem)[i] = 0;
    for (int i = tid; i < 2 * 32 * 32; i += 1024) ((unsigned short*)(smem + 33792))[i] = 0;
    const int c = wave * 16 + c16;
    const float brc = bih0[c] + bhh0[c];
    const float bzc = bih0[HID + c] + bhh0[HID + c];
    const float bni = bih0[2 * HID + c];
    const float bnh = bhh0[2 * HID + c];
    {  // x(0)
      int r = tid & 31, cc = tid >> 5;
      float xv = x[(size_t)(row0 + r) * IN_DIM + (cc < 18 ? cc : 17)];
      if (cc < 18) xs[r][cc] = f2bf(xv);
    }
    __syncthreads();

    const uint32_t b0r = (uint32_t)((wave * KT0) << 10);
    const uint32_t b0z = (uint32_t)(((16 + wave) * KT0) << 10);
    const uint32_t b0n = (uint32_t)(((32 + wave) * KT0) << 10);
    frag_ab rr_[3], rz_[3], rn_[3];
    float h1m[2][4] = {{0, 0, 0, 0}, {0, 0, 0, 0}};
    uint32_t xvu = 0;
    #pragma unroll
    for (int i = 0; i < 3; ++i)
      ISSUE3(i, b0r + i * 1024 + lane16, b0z + i * 1024 + lane16,
                b0n + i * 1024 + lane16);

    for (int t = 0; t < T_STEPS; ++t) {
      const int p = t & 1, pn = p ^ 1;
      {  // x(t+1) prefetch (plain cached load)
        int t1 = (t + 1 < T_STEPS) ? t + 1 : T_STEPS - 1;
        int r = tid & 31, cc = tid >> 5;
        uint32_t xo = (uint32_t)((((t1 * BATCH) + row0 + r) * IN_DIM +
                                  (cc < 18 ? cc : 17)) * 4);
        asm volatile("global_load_dword %0, %1, %2"
                     : "=&v"(xvu) : "v"(xo), "s"(x) : "memory");
      }
      f32x4 a_r[2] = {{0,0,0,0},{0,0,0,0}}, a_z[2] = {{0,0,0,0},{0,0,0,0}};
      f32x4 a_nx[2] = {{0,0,0,0},{0,0,0,0}}, a_nh[2] = {{0,0,0,0},{0,0,0,0}};
      #pragma unroll
      for (int i = 0; i < KT0; ++i) {
        const int sl = i % 3;
        WAIT3(sl, "6");
        frag_ab A0, A1v;
        if (i == 0) {
          A0  = *(const frag_ab*)&xs[p * 32 + c16][q * 8];
          A1v = *(const frag_ab*)&xs[p * 32 + 16 + c16][q * 8];
        } else {
          A0  = *(const frag_ab*)&h1b[p * 32 + c16][(i - 1) * 32 + q * 8];
          A1v = *(const frag_ab*)&h1b[p * 32 + 16 + c16][(i - 1) * 32 + q * 8];
        }
        a_r[0] = mfma16(A0, rr_[sl], a_r[0]);  a_r[1] = mfma16(A1v, rr_[sl], a_r[1]);
        a_z[0] = mfma16(A0, rz_[sl], a_z[0]);  a_z[1] = mfma16(A1v, rz_[sl], a_z[1]);
        if (i == 0) { a_nx[0] = mfma16(A0, rn_[sl], a_nx[0]);
                      a_nx[1] = mfma16(A1v, rn_[sl], a_nx[1]); }
        else        { a_nh[0] = mfma16(A0, rn_[sl], a_nh[0]);
                      a_nh[1] = mfma16(A1v, rn_[sl], a_nh[1]); }
        const int nk = (i + 3) % KT0;
        ISSUE3(sl, b0r + nk * 1024 + lane16, b0z + nk * 1024 + lane16,
                   b0n + nk * 1024 + lane16);
      }
      // epilogue: x(t+1) stage + h1 update
      { int r = tid & 31, cc = tid >> 5;
        if (cc < 18) xs[pn * 32 + r][cc] = f2bf(__uint_as_float(xvu)); }
      #pragma unroll
      for (int mt = 0; mt < 2; ++mt)
        #pragma unroll
        for (int rrI = 0; rrI < 4; ++rrI) {
          const int row = mt * 16 + q * 4 + rrI;
          float rg = sigmoidf_(a_r[mt][rrI] + brc);
          float zg = sigmoidf_(a_z[mt][rrI] + bzc);
          float ng = tanhf_(a_nx[mt][rrI] + bni + rg * (a_nh[mt][rrI] + bnh));
          float hn = (1.f - zg) * ng + zg * h1m[mt][rrI];
          h1m[mt][rrI] = hn;
          h1b[pn * 32 + row][c] = f2bf(hn);
        }
      BARRIER();
      {  // export frag j = wave (A-operand layout for BC)
        const int mt = wave >> 3, kt = wave & 7;
        frag_ab fa = *(const frag_ab*)&h1b[pn * 32 + mt * 16 + c16][kt * 32 + q * 8];
        SCSTORE4(H1SLOT(t, g) + (uint32_t)(wave * 1024 + lane * 16), fa);
      }
      asm volatile("s_waitcnt vmcnt(0)" ::: "memory");
      BARRIER();
      if (tid == 0) {
        PUBLISH(CNTA(g), t + 1);
        POLL(CNTB1(g), t - 3);
        POLL(CNTB2(g), t - 3);
      }
      BARRIER();
    }

  } else {
    // ------------- Stage BC: layer-1 fused (column half hf) ---------------
    const int g  = (bid - 64) >> 1;
    const int hf = (bid - 64) & 1;
    const int row0 = g * 32;
    unsigned short* slab = (unsigned short*)smem;                        // 32 KB (2x16K h1 frag slabs)
    unsigned short (*h2b)[264] = (unsigned short (*)[264])(smem + 32768); // [2*32][264] = 33792 B
    f32x4* exch4 = (f32x4*)(smem + 66560);                               // 48 KB wave-pair partials
    const int ct   = wave & 7;       // local col-tile
    const int half = wave >> 3;      // 0: xg GEMM, 1: hg GEMM
    const int cl   = ct * 16 + c16;  // local col [0,128)
    const int c    = hf * 128 + cl;  // global col [0,256)
    const float bri = bih1[c],           brh = bhh1[c];
    const float bzi = bih1[HID + c],     bzh = bhh1[HID + c];
    const float bni = bih1[2 * HID + c], bnh = bhh1[2 * HID + c];
    for (int i = tid; i < 2 * 32 * 264; i += 1024)
      ((unsigned short*)(smem + 32768))[i] = 0;
    if (tid == 0) POLL(CNTA(g), 1);
    BARRIER();
    { uint4v u; SCLOAD4(u, H1SLOT(0, g) + tid * 16);
      asm volatile("s_waitcnt vmcnt(0)" : "+v"(u) :: "memory");
      *(uint4v*)((char*)slab + tid * 16) = u; }
    if (tid == 0) POLL(CNTA(g), 2);
    __syncthreads();

    // weight frag bases: N-tiles for (r,z,n) of this column half;
    // kt 0-7 = W_ih1 (half 0), kt 8-15 = W_hh1 (half 1)
    const int nR = hf * 8 + ct, nZ = 16 + hf * 8 + ct, nN = 32 + hf * 8 + ct;
    const uint32_t bR = (uint32_t)((L0_FRAGS + nR * KT1 + half * 8) << 10);
    const uint32_t bZ = (uint32_t)((L0_FRAGS + nZ * KT1 + half * 8) << 10);
    const uint32_t bN = (uint32_t)((L0_FRAGS + nN * KT1 + half * 8) << 10);
    frag_ab rr_[4], rz_[4], rn_[4];
    float h2m[4] = {0, 0, 0, 0};     // h2 state for this wave's M-tile (mt = half)
    #pragma unroll
    for (int i = 0; i < 4; ++i)
      ISSUE3(i, bR + i * 1024 + lane16, bZ + i * 1024 + lane16,
                bN + i * 1024 + lane16);

    for (int t = 0; t < T_STEPS; ++t) {
      const int p = t & 1, pn = p ^ 1;
      uint4v stg = {0, 0, 0, 0};
      const bool hasst = (t + 1 < T_STEPS);
      if (hasst) SCLOAD4(stg, H1SLOT(t + 1, g) + tid * 16);
      f32x4 acc[3][2];
      #pragma unroll
      for (int ga = 0; ga < 3; ++ga) { acc[ga][0] = (f32x4){0,0,0,0};
                                       acc[ga][1] = (f32x4){0,0,0,0}; }
      #pragma unroll
      for (int i = 0; i < 8; ++i) {
        const int sl = i & 3;
        WAIT3(sl, "9");
        frag_ab A0, A1v;
        if (half == 0) {  // A = h1(t) frags
          A0  = *(const frag_ab*)((char*)slab + p * 16384 + (i * 64 + lane) * 16);
          A1v = *(const frag_ab*)((char*)slab + p * 16384 + ((8 + i) * 64 + lane) * 16);
        } else {          // A = h2(t-1)
          A0  = *(const frag_ab*)&h2b[p * 32 + c16][i * 32 + q * 8];
          A1v = *(const frag_ab*)&h2b[p * 32 + 16 + c16][i * 32 + q * 8];
        }
        acc[0][0] = mfma16(A0, rr_[sl], acc[0][0]); acc[0][1] = mfma16(A1v, rr_[sl], acc[0][1]);
        acc[1][0] = mfma16(A0, rz_[sl], acc[1][0]); acc[1][1] = mfma16(A1v, rz_[sl], acc[1][1]);
        acc[2][0] = mfma16(A0, rn_[sl], acc[2][0]); acc[2][1] = mfma16(A1v, rn_[sl], acc[2][1]);
        const int nk = (i + 4) & 7;
        ISSUE3(sl, bR + nk * 1024 + lane16, bZ + nk * 1024 + lane16,
                   bN + nk * 1024 + lane16);
      }
      if (hasst) *(uint4v*)((char*)slab + pn * 16384 + tid * 16) = stg;
      // wave-pair partial exchange: give away the M-tile we don't finish
      // (static indexing only: half is runtime, avoid acc[ga][half] -> scratch)
      {
        f32x4 g0 = half ? acc[0][0] : acc[0][1];
        f32x4 g1 = half ? acc[1][0] : acc[1][1];
        f32x4 g2 = half ? acc[2][0] : acc[2][1];
        exch4[((ct * 2 + half) * 3 + 0) * 64 + lane] = g0;
        exch4[((ct * 2 + half) * 3 + 1) * 64 + lane] = g1;
        exch4[((ct * 2 + half) * 3 + 2) * 64 + lane] = g2;
      }
      BARRIER();
      // epilogue for M-tile mt = half: combine own + partner partials
      {
        f32x4 oth0 = exch4[((ct * 2 + (half ^ 1)) * 3 + 0) * 64 + lane];
        f32x4 oth1 = exch4[((ct * 2 + (half ^ 1)) * 3 + 1) * 64 + lane];
        f32x4 oth2 = exch4[((ct * 2 + (half ^ 1)) * 3 + 2) * 64 + lane];
        f32x4 own0 = half ? acc[0][1] : acc[0][0];
        f32x4 own1 = half ? acc[1][1] : acc[1][0];
        f32x4 own2 = half ? acc[2][1] : acc[2][0];
        #pragma unroll
        for (int j = 0; j < 4; ++j) {
          float xr = half ? oth0[j] : own0[j];
          float hr = half ? own0[j] : oth0[j];
          float xz = half ? oth1[j] : own1[j];
          float hz = half ? own1[j] : oth1[j];
          float xn = half ? oth2[j] : own2[j];
          float hn = half ? own2[j] : oth2[j];
          float rg = sigmoidf_(xr + bri + hr + brh);
          float zg = sigmoidf_(xz + bzi + hz + bzh);
          float ng = tanhf_(xn + bni + rg * (hn + bnh));
          float hv = (1.f - zg) * ng + zg * h2m[j];
          h2m[j] = hv;
          unsigned short hb = f2bf(hv);
          const int row = half * 16 + q * 4 + j;
          h2b[pn * 32 + row][c] = hb;
          // export own half, row-major [32][128] bf16
          SCSTOREH(PSLOT(t, g, hf) + (uint32_t)((row * 128 + cl) * 2),
                   (uint32_t)hb);
        }
      }
      asm volatile("s_waitcnt vmcnt(0)" ::: "memory");
      BARRIER();
      if (tid == 0) {
        PUBLISH(hf ? CNTB2(g) : CNTB1(g), t + 1);
        if (t <= 125) POLL(CNTA(g), t + 3);
        POLL(hf ? CNTB1(g) : CNTB2(g), t + 1);
      }
      BARRIER();
      // receive partner's h2 half into h2b[pn]
      if (tid < 512) {
        const int rrow = tid >> 4, cb = tid & 15;
        uint4v u;
        SCLOAD4(u, PSLOT(t, g, hf ^ 1) + (uint32_t)(tid * 16));
        asm volatile("s_waitcnt vmcnt(0)" : "+v"(u) :: "memory");
        *(uint4v*)&h2b[pn * 32 + rrow][(hf ^ 1) * 128 + cb * 8] = u;
      }
      BARRIER();
    }

    // FC head from h2b parity 0 (h2(127): pn of t=127 is 0); hf=0 block only
    if (hf == 0 && tid < 128) {
      const int row = tid >> 2, o = tid & 3;
      float acc2 = fcb[o];
      #pragma unroll 8
      for (int k = 0; k < HID; ++k)
        acc2 += bf2f(h2b[row][k]) * fcw[o * HID + k];
      float sg = 1.f / (1.f + __expf(-acc2));
      out[(size_t)(row0 + row) * 4 + o] = sg * 2.f - 1.f;
    }
  }
#undef BARRIER
#undef ISSUE3
#undef WAIT3
#undef SCLOAD4
#undef SCSTORE4
#undef SCSTOREH
#undef PUBLISH
#undef POLL
}

extern "C" void kernel_launch(void* const* d_in, const int* in_sizes, int n_in,
                              void* d_out, int out_size, void* d_ws, size_t ws_size,
                              hipStream_t stream) {
  const float* x    = (const float*)d_in[0];
  const float* Wih0 = (const float*)d_in[1];
  const float* Whh0 = (const float*)d_in[2];
  const float* bih0 = (const float*)d_in[3];
  const float* bhh0 = (const float*)d_in[4];
  const float* Wih1 = (const float*)d_in[5];
  const float* Whh1 = (const float*)d_in[6];
  const float* bih1 = (const float*)d_in[7];
  const float* bhh1 = (const float*)d_in[8];
  const float* fcw  = (const float*)d_in[9];
  const float* fcb  = (const float*)d_in[10];

  unsigned short* wq = (unsigned short*)d_ws;
  uint32_t* cnt = (uint32_t*)((char*)d_ws + CNT_OFF);

  repack_w<<<(TOT_FRAGS * 64 + 255) / 256, 256, 0, stream>>>(Wih0, Whh0, Wih1, Whh1, wq);
  clear_cnt<<<12, 256, 0, stream>>>(cnt);
  gru_pipe<<<192, 1024, 0, stream>>>(x, bih0, bhh0, bih1, bhh1, fcw, fcb,
                                     (char*)d_ws, (float*)d_out);
}

// Round 2
// 1095.298 us; speedup vs baseline: 1.0150x; 1.0150x over previous
//
#include <hip/hip_runtime.h>
#include <hip/hip_bf16.h>
#include <stdint.h>

// Problem constants
#define T_STEPS 128
#define BATCH   2048
#define IN_DIM  18
#define HID     256

// Fragment repack (same layout as R3)
#define NT   48
#define KT0  9
#define KT1  16
#define L0_FRAGS 432
#define L1_FRAGS 768
#define TOT_FRAGS 1200

// d_ws layout (total need ~17.7 MB)
#define CNT_OFF  1310720u
#define CNTA(g)  (CNT_OFF + (uint32_t)(g) * 64u)
#define CNTB(g)  (CNT_OFF + 4096u + (uint32_t)(g) * 64u)
#define CNTC(g)  (CNT_OFF + 8192u + (uint32_t)(g) * 64u)
#define H1_OFF   1441792u
#define H1SLOT(t, g) (H1_OFF + (uint32_t)(((((t) & 3) * 64) + (g)) * 16384))
#define XG_OFF   5898240u
#define XGSLOT(t, g) (XG_OFF + (uint32_t)(((((t) & 3) * 64) + (g)) * 49152))

// xg in-slab layout: col-major 64B rows, XOR-swizzled to break the 8-way
// bank conflict on C's gate reads (banks were {0,16} only at 64B stride).
#define XGOFFS(col, inner) ((uint32_t)((col) * 64 + ((inner) ^ (((col) & 7) << 3))))

using frag_ab = __attribute__((ext_vector_type(8))) short;
using f32x4   = __attribute__((ext_vector_type(4))) float;
using uint4v  = __attribute__((ext_vector_type(4))) unsigned int;
using uint2v  = __attribute__((ext_vector_type(2))) unsigned int;

__device__ __forceinline__ unsigned short f2bf(float f) {
  unsigned int u = __float_as_uint(f);
  u = (u + 0x7fffu + ((u >> 16) & 1u)) >> 16;  // RNE
  return (unsigned short)u;
}
__device__ __forceinline__ float bf2f(unsigned short v) {
  return __uint_as_float((uint32_t)v << 16);
}
__device__ __forceinline__ float sigmoidf_(float v) {
  return 1.f / (1.f + __expf(-v));
}
__device__ __forceinline__ float tanhf_(float v) {
  float a = fabsf(v);
  float e = __expf(-2.f * a);
  float r = (1.f - e) / (1.f + e);
  return v < 0.f ? -r : r;
}
__device__ __forceinline__ f32x4 mfma16(frag_ab a, frag_ab b, f32x4 c) {
  return __builtin_amdgcn_mfma_f32_16x16x32_bf16(a, b, c, 0, 0, 0);
}

// ---------------------------------------------------------------------------
// Prologue 1: fp32 weights -> bf16 MFMA B-fragments (layout as R3).
// ---------------------------------------------------------------------------
__global__ __launch_bounds__(256) void repack_w(
    const float* __restrict__ Wih0, const float* __restrict__ Whh0,
    const float* __restrict__ Wih1, const float* __restrict__ Whh1,
    unsigned short* __restrict__ wq)
{
  int g = blockIdx.x * 256 + threadIdx.x;
  if (g >= TOT_FRAGS * 64) return;
  int f = g >> 6;
  int L = g & 63;
  int q = L >> 4, c16 = L & 15;
  unsigned short v[8];
  if (f < L0_FRAGS) {
    int n = f / KT0, kt = f - n * KT0;
    int col = n * 16 + c16;
    if (kt == 0) {
      #pragma unroll
      for (int j = 0; j < 8; ++j) {
        int k = q * 8 + j;
        v[j] = (k < IN_DIM) ? f2bf(Wih0[col * IN_DIM + k]) : (unsigned short)0;
      }
    } else {
      int kb = (kt - 1) * 32 + q * 8;
      #pragma unroll
      for (int j = 0; j < 8; ++j) v[j] = f2bf(Whh0[col * HID + kb + j]);
    }
  } else {
    int f1 = f - L0_FRAGS;
    int n = f1 / KT1, kt = f1 - n * KT1;
    int col = n * 16 + c16;
    const float* __restrict__ W = (kt < 8) ? Wih1 : Whh1;
    int kb = (kt & 7) * 32 + q * 8;
    #pragma unroll
    for (int j = 0; j < 8; ++j) v[j] = f2bf(W[col * HID + kb + j]);
  }
  frag_ab pv;
  #pragma unroll
  for (int j = 0; j < 8; ++j) pv[j] = (short)v[j];
  *(frag_ab*)((char*)wq + ((size_t)f << 10) + (size_t)(L << 4)) = pv;
}

// ---------------------------------------------------------------------------
// Prologue 2: zero the counters (d_ws poisoned each launch).
// ---------------------------------------------------------------------------
__global__ __launch_bounds__(256) void clear_cnt(uint32_t* __restrict__ c) {
  int i = blockIdx.x * 256 + threadIdx.x;
  if (i < 3072) c[i] = 0;
}

// ---------------------------------------------------------------------------
// 3-stage pipeline: A (layer0) -> B (h1 @ W_ih1^T) -> C (h2 recurrence + FC).
// R0 topology. R2 changes:
//  - pipelined stale-credit sync: tid0 preloads the partner counter one step
//    ahead (retired for free by the export vmcnt(0) drain) and only spins on
//    a stale miss. Monotonic counters => stale >= target is always safe.
//  - stage A's trailing barrier removed (epilogue barrier of the next step
//    already orders tid0's credit check before the guarded export).
//  - xg slab XOR-swizzle (XGOFFS) writer+reader to kill C's 8-way LDS bank
//    conflict on the gate reads.
// ---------------------------------------------------------------------------
__global__ __launch_bounds__(1024) void gru_pipe(
    const float* __restrict__ x,
    const float* __restrict__ bih0, const float* __restrict__ bhh0,
    const float* __restrict__ bih1, const float* __restrict__ bhh1,
    const float* __restrict__ fcw,  const float* __restrict__ fcb,
    char* __restrict__ ws,
    float* __restrict__ out)
{
  __shared__ __align__(16) char smem[82944];   // 81 KB -> 1 block/CU

  const int tid  = threadIdx.x;
  const int wave = tid >> 6;
  const int lane = tid & 63;
  const int q    = lane >> 4;
  const int c16  = lane & 15;
  const int bid  = blockIdx.x;
  const uint32_t lane16 = (uint32_t)(lane << 4);
  int dead = 0;

#define BARRIER() asm volatile("s_waitcnt lgkmcnt(0)\n\ts_barrier" ::: "memory")
#define ISSUE3(sl, oR, oZ, oN)                                              \
  asm volatile("global_load_dwordx4 %0, %3, %6\n\t"                         \
               "global_load_dwordx4 %1, %4, %6\n\t"                         \
               "global_load_dwordx4 %2, %5, %6"                             \
               : "=&v"(rr_[sl]), "=&v"(rz_[sl]), "=&v"(rn_[sl])             \
               : "v"((uint32_t)(oR)), "v"((uint32_t)(oZ)),                  \
                 "v"((uint32_t)(oN)), "s"(ws)                               \
               : "memory")
#define WAIT3(sl, NSTR)                                                     \
  asm volatile("s_waitcnt vmcnt(" NSTR ")"                                  \
               : "+v"(rr_[sl]), "+v"(rz_[sl]), "+v"(rn_[sl]) :: "memory")
#define SCLOAD4(dst, off)                                                   \
  asm volatile("global_load_dwordx4 %0, %1, %2 sc0 sc1"                     \
               : "=&v"(dst) : "v"((uint32_t)(off)), "s"(ws) : "memory")
#define SCSTORE4(off, val)                                                  \
  asm volatile("global_store_dwordx4 %0, %1, %2 sc0 sc1"                    \
               :: "v"((uint32_t)(off)), "v"(val), "s"(ws) : "memory")
#define SCSTORE2(off, val)                                                  \
  asm volatile("global_store_dwordx2 %0, %1, %2 sc0 sc1"                    \
               :: "v"((uint32_t)(off)), "v"(val), "s"(ws) : "memory")
#define PUBLISH(off, val)                                                   \
  asm volatile("global_store_dword %0, %1, %2 sc0 sc1"                      \
               :: "v"((uint32_t)(off)), "v"((uint32_t)(val)), "s"(ws)       \
               : "memory")
#define CREDLOAD(dst, off)                                                  \
  asm volatile("global_load_dword %0, %1, %2 sc0 sc1"                       \
               : "=&v"(dst) : "v"((uint32_t)(off)), "s"(ws) : "memory")
#define POLL(off, target)                                                   \
  do {                                                                      \
    int tgt = (target);                                                     \
    if (tgt > 0) {                                                          \
      int it = 0, bound = dead ? 64 : (1 << 17);                            \
      for (;;) {                                                            \
        uint32_t v_;                                                        \
        asm volatile("global_load_dword %0, %1, %2 sc0 sc1\n\t"             \
                     "s_waitcnt vmcnt(0)"                                   \
                     : "=&v"(v_) : "v"((uint32_t)(off)), "s"(ws)            \
                     : "memory");                                           \
        if ((int)v_ >= tgt) break;                                          \
        if (++it >= bound) { dead = 1; break; }                             \
        __builtin_amdgcn_s_sleep(2);                                        \
      }                                                                     \
    }                                                                       \
  } while (0)

  // =========================================================================
  if (bid < 64) {
    // ----------------------------- Stage A: layer 0 -----------------------
    const int g = bid, row0 = g * 32;
    unsigned short (*h1b)[264] = (unsigned short (*)[264])smem;       // [2*32][264]
    unsigned short (*xs)[32]   = (unsigned short (*)[32])(smem + 33792); // [2*32][32]
    for (int i = tid; i < 2 * 32 * 264; i += 1024) ((unsigned short*)smem)[i] = 0;
    for (int i = tid; i < 2 * 32 * 32; i += 1024) ((unsigned short*)(smem + 33792))[i] = 0;
    const int c = wave * 16 + c16;
    const float brc = bih0[c] + bhh0[c];
    const float bzc = bih0[HID + c] + bhh0[HID + c];
    const float bni = bih0[2 * HID + c];
    const float bnh = bhh0[2 * HID + c];
    {  // x(0)
      int r = tid & 31, cc = tid >> 5;
      float xv = x[(size_t)(row0 + r) * IN_DIM + (cc < 18 ? cc : 17)];
      if (cc < 18) xs[r][cc] = f2bf(xv);
    }
    __syncthreads();

    const uint32_t b0r = (uint32_t)((wave * KT0) << 10);
    const uint32_t b0z = (uint32_t)(((16 + wave) * KT0) << 10);
    const uint32_t b0n = (uint32_t)(((32 + wave) * KT0) << 10);
    frag_ab rr_[3], rz_[3], rn_[3];
    float h1m[2][4] = {{0, 0, 0, 0}, {0, 0, 0, 0}};
    uint32_t xvu = 0;
    uint32_t credB = 0;
    #pragma unroll
    for (int i = 0; i < 3; ++i)
      ISSUE3(i, b0r + i * 1024 + lane16, b0z + i * 1024 + lane16,
                b0n + i * 1024 + lane16);

    for (int t = 0; t < T_STEPS; ++t) {
      const int p = t & 1, pn = p ^ 1;
      {  // x(t+1) prefetch (plain cached load)
        int t1 = (t + 1 < T_STEPS) ? t + 1 : T_STEPS - 1;
        int r = tid & 31, cc = tid >> 5;
        uint32_t xo = (uint32_t)((((t1 * BATCH) + row0 + r) * IN_DIM +
                                  (cc < 18 ? cc : 17)) * 4);
        asm volatile("global_load_dword %0, %1, %2"
                     : "=&v"(xvu) : "v"(xo), "s"(x) : "memory");
      }
      f32x4 a_r[2] = {{0,0,0,0},{0,0,0,0}}, a_z[2] = {{0,0,0,0},{0,0,0,0}};
      f32x4 a_nx[2] = {{0,0,0,0},{0,0,0,0}}, a_nh[2] = {{0,0,0,0},{0,0,0,0}};
      #pragma unroll
      for (int i = 0; i < KT0; ++i) {
        const int sl = i % 3;
        WAIT3(sl, "6");
        frag_ab A0, A1v;
        if (i == 0) {
          A0  = *(const frag_ab*)&xs[p * 32 + c16][q * 8];
          A1v = *(const frag_ab*)&xs[p * 32 + 16 + c16][q * 8];
        } else {
          A0  = *(const frag_ab*)&h1b[p * 32 + c16][(i - 1) * 32 + q * 8];
          A1v = *(const frag_ab*)&h1b[p * 32 + 16 + c16][(i - 1) * 32 + q * 8];
        }
        a_r[0] = mfma16(A0, rr_[sl], a_r[0]);  a_r[1] = mfma16(A1v, rr_[sl], a_r[1]);
        a_z[0] = mfma16(A0, rz_[sl], a_z[0]);  a_z[1] = mfma16(A1v, rz_[sl], a_z[1]);
        if (i == 0) { a_nx[0] = mfma16(A0, rn_[sl], a_nx[0]);
                      a_nx[1] = mfma16(A1v, rn_[sl], a_nx[1]); }
        else        { a_nh[0] = mfma16(A0, rn_[sl], a_nh[0]);
                      a_nh[1] = mfma16(A1v, rn_[sl], a_nh[1]); }
        const int nk = (i + 3) % KT0;
        ISSUE3(sl, b0r + nk * 1024 + lane16, b0z + nk * 1024 + lane16,
                   b0n + nk * 1024 + lane16);
      }
      // epilogue: x(t+1) stage + h1 update
      { int r = tid & 31, cc = tid >> 5;
        if (cc < 18) xs[pn * 32 + r][cc] = f2bf(__uint_as_float(xvu)); }
      #pragma unroll
      for (int mt = 0; mt < 2; ++mt)
        #pragma unroll
        for (int rrI = 0; rrI < 4; ++rrI) {
          const int row = mt * 16 + q * 4 + rrI;
          float rg = sigmoidf_(a_r[mt][rrI] + brc);
          float zg = sigmoidf_(a_z[mt][rrI] + bzc);
          float ng = tanhf_(a_nx[mt][rrI] + bni + rg * (a_nh[mt][rrI] + bnh));
          float hn = (1.f - zg) * ng + zg * h1m[mt][rrI];
          h1m[mt][rrI] = hn;
          h1b[pn * 32 + row][c] = f2bf(hn);
        }
      BARRIER();   // h1b[pn] ready; also orders tid0's credit check (t-1)
                   // before this step's export.
      {  // export frag j = wave (A-operand layout for B)
        const int mt = wave >> 3, kt = wave & 7;
        frag_ab fa = *(const frag_ab*)&h1b[pn * 32 + mt * 16 + c16][kt * 32 + q * 8];
        SCSTORE4(H1SLOT(t, g) + (uint32_t)(wave * 1024 + lane * 16), fa);
      }
      asm volatile("s_waitcnt vmcnt(0)" ::: "memory");
      BARRIER();
      if (tid == 0) {
        PUBLISH(CNTA(g), t + 1);
        // stale-credit: only spin if last step's snapshot misses the target
        if ((int)credB < t - 3) POLL(CNTB(g), t - 3);
        CREDLOAD(credB, CNTB(g));   // retired by next step's vmcnt(0)
      }
      // no trailing barrier: next epilogue barrier broadcasts the check
    }

  } else if (bid < 128) {
    // ------------------------ Stage B: xg1 = h1 @ W_ih1^T -----------------
    const int g = bid - 64;
    unsigned short* slab = (unsigned short*)smem;   // [2][16384 B] frag slabs
    const int c = wave * 16 + c16;
    const float bri = bih1[c], bzi = bih1[HID + c], bni = bih1[2 * HID + c];
    if (tid == 0) POLL(CNTA(g), 1);
    BARRIER();
    { uint4v u; SCLOAD4(u, H1SLOT(0, g) + tid * 16);
      asm volatile("s_waitcnt vmcnt(0)" : "+v"(u) :: "memory");
      *(uint4v*)((char*)slab + tid * 16) = u; }
    if (tid == 0) POLL(CNTA(g), 2);
    __syncthreads();

    const uint32_t b1r = (uint32_t)((L0_FRAGS + wave * KT1) << 10);
    const uint32_t b1z = (uint32_t)((L0_FRAGS + (16 + wave) * KT1) << 10);
    const uint32_t b1n = (uint32_t)((L0_FRAGS + (32 + wave) * KT1) << 10);
    frag_ab rr_[4], rz_[4], rn_[4];
    uint32_t credA = 2, credC = 0;
    #pragma unroll
    for (int i = 0; i < 4; ++i)
      ISSUE3(i, b1r + i * 1024 + lane16, b1z + i * 1024 + lane16,
                b1n + i * 1024 + lane16);

    for (int t = 0; t < T_STEPS; ++t) {
      const int p = t & 1, pn = p ^ 1;
      uint4v stg = {0, 0, 0, 0};
      const bool hasst = (t + 1 < T_STEPS);
      if (hasst) SCLOAD4(stg, H1SLOT(t + 1, g) + tid * 16);
      f32x4 acc[3][2];
      #pragma unroll
      for (int ga = 0; ga < 3; ++ga) { acc[ga][0] = (f32x4){0,0,0,0};
                                       acc[ga][1] = (f32x4){0,0,0,0}; }
      #pragma unroll
      for (int i = 0; i < 8; ++i) {
        const int sl = i & 3;
        WAIT3(sl, "9");
        frag_ab A0  = *(const frag_ab*)((char*)slab + p * 16384 + (i * 64 + lane) * 16);
        frag_ab A1v = *(const frag_ab*)((char*)slab + p * 16384 + ((8 + i) * 64 + lane) * 16);
        acc[0][0] = mfma16(A0, rr_[sl], acc[0][0]); acc[0][1] = mfma16(A1v, rr_[sl], acc[0][1]);
        acc[1][0] = mfma16(A0, rz_[sl], acc[1][0]); acc[1][1] = mfma16(A1v, rz_[sl], acc[1][1]);
        acc[2][0] = mfma16(A0, rn_[sl], acc[2][0]); acc[2][1] = mfma16(A1v, rn_[sl], acc[2][1]);
        const int nk = (i + 4) & 7;
        ISSUE3(sl, b1r + nk * 1024 + lane16, b1z + nk * 1024 + lane16,
                   b1n + nk * 1024 + lane16);
      }
      if (hasst) *(uint4v*)((char*)slab + pn * 16384 + tid * 16) = stg;
      #pragma unroll
      for (int ga = 0; ga < 3; ++ga) {
        const float bb = (ga == 0) ? bri : (ga == 1) ? bzi : bni;
        const int col = ga * 256 + c;
        #pragma unroll
        for (int mt = 0; mt < 2; ++mt) {
          uint2v u;
          u[0] = (uint32_t)f2bf(acc[ga][mt][0] + bb) |
                 ((uint32_t)f2bf(acc[ga][mt][1] + bb) << 16);
          u[1] = (uint32_t)f2bf(acc[ga][mt][2] + bb) |
                 ((uint32_t)f2bf(acc[ga][mt][3] + bb) << 16);
          SCSTORE2(XGSLOT(t, g) + XGOFFS(col, (mt * 16 + q * 4) * 2), u);
        }
      }
      asm volatile("s_waitcnt vmcnt(0)" ::: "memory");
      BARRIER();
      if (tid == 0) {
        PUBLISH(CNTB(g), t + 1);
        if (t <= 125 && (int)credA < t + 3) POLL(CNTA(g), t + 3);
        if ((int)credC < t - 3) POLL(CNTC(g), t - 3);
        if (t <= 125) CREDLOAD(credA, CNTA(g));
        CREDLOAD(credC, CNTC(g));
      }
      BARRIER();   // needed: guards all waves' SCLOAD of H1SLOT(t+2)
    }

  } else {
    // ---------------- Stage C: h2 recurrence (W_hh1) + gates + FC ---------
    const int g = bid - 128, row0 = g * 32;
    unsigned short* xg = (unsigned short*)smem;                       // 48 KB
    unsigned short (*h2b)[264] = (unsigned short (*)[264])(smem + 49152);
    for (int i = tid; i < 2 * 32 * 264; i += 1024)
      ((unsigned short*)(smem + 49152))[i] = 0;
    const int c = wave * 16 + c16;
    const float brh = bhh1[c], bzh = bhh1[HID + c], bnh = bhh1[2 * HID + c];
    if (tid == 0) POLL(CNTB(g), 1);
    BARRIER();
    { uint4v u0, u1, u2;
      SCLOAD4(u0, XGSLOT(0, g) + tid * 16);
      SCLOAD4(u1, XGSLOT(0, g) + 16384 + tid * 16);
      SCLOAD4(u2, XGSLOT(0, g) + 32768 + tid * 16);
      asm volatile("s_waitcnt vmcnt(0)" : "+v"(u0), "+v"(u1), "+v"(u2) :: "memory");
      *(uint4v*)((char*)xg + tid * 16) = u0;
      *(uint4v*)((char*)xg + 16384 + tid * 16) = u1;
      *(uint4v*)((char*)xg + 32768 + tid * 16) = u2; }
    if (tid == 0) POLL(CNTB(g), 2);
    __syncthreads();

    const uint32_t bCr = (uint32_t)((L0_FRAGS + wave * KT1 + 8) << 10);
    const uint32_t bCz = (uint32_t)((L0_FRAGS + (16 + wave) * KT1 + 8) << 10);
    const uint32_t bCn = (uint32_t)((L0_FRAGS + (32 + wave) * KT1 + 8) << 10);
    frag_ab rr_[4], rz_[4], rn_[4];
    float h2m[2][4] = {{0, 0, 0, 0}, {0, 0, 0, 0}};
    uint32_t credB = 2;
    #pragma unroll
    for (int i = 0; i < 4; ++i)
      ISSUE3(i, bCr + i * 1024 + lane16, bCz + i * 1024 + lane16,
                bCn + i * 1024 + lane16);

    for (int t = 0; t < T_STEPS; ++t) {
      const int p = t & 1, pn = p ^ 1;
      uint4v s0 = {0,0,0,0}, s1 = {0,0,0,0}, s2 = {0,0,0,0};
      const bool hasst = (t + 1 < T_STEPS);
      if (hasst) {
        SCLOAD4(s0, XGSLOT(t + 1, g) + tid * 16);
        SCLOAD4(s1, XGSLOT(t + 1, g) + 16384 + tid * 16);
        SCLOAD4(s2, XGSLOT(t + 1, g) + 32768 + tid * 16);
      }
      f32x4 acc[3][2];
      #pragma unroll
      for (int ga = 0; ga < 3; ++ga) { acc[ga][0] = (f32x4){0,0,0,0};
                                       acc[ga][1] = (f32x4){0,0,0,0}; }
      #pragma unroll
      for (int i = 0; i < 8; ++i) {
        const int sl = i & 3;
        WAIT3(sl, "9");
        frag_ab A0  = *(const frag_ab*)&h2b[p * 32 + c16][i * 32 + q * 8];
        frag_ab A1v = *(const frag_ab*)&h2b[p * 32 + 16 + c16][i * 32 + q * 8];
        acc[0][0] = mfma16(A0, rr_[sl], acc[0][0]); acc[0][1] = mfma16(A1v, rr_[sl], acc[0][1]);
        acc[1][0] = mfma16(A0, rz_[sl], acc[1][0]); acc[1][1] = mfma16(A1v, rz_[sl], acc[1][1]);
        acc[2][0] = mfma16(A0, rn_[sl], acc[2][0]); acc[2][1] = mfma16(A1v, rn_[sl], acc[2][1]);
        const int nk = (i + 4) & 7;
        ISSUE3(sl, bCr + nk * 1024 + lane16, bCz + nk * 1024 + lane16,
                   bCn + nk * 1024 + lane16);
      }
      // epilogue: read xg(t) from LDS (swizzled layout), gates, h2 update
      #pragma unroll
      for (int mt = 0; mt < 2; ++mt) {
        uint2v ur = *(const uint2v*)((char*)xg + XGOFFS(0 * 256 + c, (mt * 16 + q * 4) * 2));
        uint2v uz = *(const uint2v*)((char*)xg + XGOFFS(1 * 256 + c, (mt * 16 + q * 4) * 2));
        uint2v un = *(const uint2v*)((char*)xg + XGOFFS(2 * 256 + c, (mt * 16 + q * 4) * 2));
        #pragma unroll
        for (int rrI = 0; rrI < 4; ++rrI) {
          const int row = mt * 16 + q * 4 + rrI;
          const uint32_t wr = (rrI < 2) ? ur[0] : ur[1];
          const uint32_t wz = (rrI < 2) ? uz[0] : uz[1];
          const uint32_t wn = (rrI < 2) ? un[0] : un[1];
          const int sh = (rrI & 1) * 16;
          float xr = bf2f((unsigned short)(wr >> sh));
          float xz = bf2f((unsigned short)(wz >> sh));
          float xn = bf2f((unsigned short)(wn >> sh));
          float rg = sigmoidf_(xr + acc[0][mt][rrI] + brh);
          float zg = sigmoidf_(xz + acc[1][mt][rrI] + bzh);
          float ng = tanhf_(xn + rg * (acc[2][mt][rrI] + bnh));
          float hn = (1.f - zg) * ng + zg * h2m[mt][rrI];
          h2m[mt][rrI] = hn;
          h2b[pn * 32 + row][c] = f2bf(hn);
        }
      }
      BARRIER();   // all xg(t) reads done before overwrite
      if (hasst) {
        *(uint4v*)((char*)xg + tid * 16) = s0;
        *(uint4v*)((char*)xg + 16384 + tid * 16) = s1;
        *(uint4v*)((char*)xg + 32768 + tid * 16) = s2;
      }
      BARRIER();
      if (tid == 0) {
        PUBLISH(CNTC(g), t + 1);
        if (t <= 125 && (int)credB < t + 3) POLL(CNTB(g), t + 3);
        if (t <= 125) CREDLOAD(credB, CNTB(g));
      }
      BARRIER();   // needed: guards all waves' SCLOAD of XGSLOT(t+2)
    }

    // FC head from h2b parity 0 (h2(127): pn of t=127 is 0)
    if (tid < 128) {
      const int row = tid >> 2, o = tid & 3;
      float acc2 = fcb[o];
      #pragma unroll 8
      for (int k = 0; k < HID; ++k)
        acc2 += bf2f(h2b[row][k]) * fcw[o * HID + k];
      float sg = 1.f / (1.f + __expf(-acc2));
      out[(size_t)(row0 + row) * 4 + o] = sg * 2.f - 1.f;
    }
  }
#undef BARRIER
#undef ISSUE3
#undef WAIT3
#undef SCLOAD4
#undef SCSTORE4
#undef SCSTORE2
#undef PUBLISH
#undef CREDLOAD
#undef POLL
}

extern "C" void kernel_launch(void* const* d_in, const int* in_sizes, int n_in,
                              void* d_out, int out_size, void* d_ws, size_t ws_size,
                              hipStream_t stream) {
  const float* x    = (const float*)d_in[0];
  const float* Wih0 = (const float*)d_in[1];
  const float* Whh0 = (const float*)d_in[2];
  const float* bih0 = (const float*)d_in[3];
  const float* bhh0 = (const float*)d_in[4];
  const float* Wih1 = (const float*)d_in[5];
  const float* Whh1 = (const float*)d_in[6];
  const float* bih1 = (const float*)d_in[7];
  const float* bhh1 = (const float*)d_in[8];
  const float* fcw  = (const float*)d_in[9];
  const float* fcb  = (const float*)d_in[10];

  unsigned short* wq = (unsigned short*)d_ws;
  uint32_t* cnt = (uint32_t*)((char*)d_ws + CNT_OFF);

  repack_w<<<(TOT_FRAGS * 64 + 255) / 256, 256, 0, stream>>>(Wih0, Whh0, Wih1, Whh1, wq);
  clear_cnt<<<12, 256, 0, stream>>>(cnt);
  gru_pipe<<<192, 1024, 0, stream>>>(x, bih0, bhh0, bih1, bhh1, fcw, fcb,
                                     (char*)d_ws, (float*)d_out);
}